// Round 3
// baseline (1060.793 us; speedup 1.0000x reference)
//
#include <hip/hip_runtime.h>

#define B_SZ 64
#define T_LEN 2048
#define NIN 257
#define HID 32
#define G4 128
#define NOUT 10

#define TBT 128         // rows per xproj tile
#define PAD 34
#define CH 8
#define NTILE 1024      // 16 t-tiles * 64 batches
#define TPB 16          // t-tiles per batch

typedef int v2i __attribute__((ext_vector_type(2)));
typedef unsigned long long u64;

// acc.x += w.x * h2.lo ; acc.y += w.y * h2.hi   (standard packed, no op_sel)
__device__ __forceinline__ void pkfma2(float2& acc, float2 w, u64 h2) {
  asm("v_pk_fma_f32 %0, %1, %2, %0" : "+v"(acc) : "v"(w), "s"(h2));
}

__device__ __forceinline__ float2 pkadd(float2 a, float2 b) {
  float2 d;
  asm("v_pk_add_f32 %0, %1, %2" : "=v"(d) : "v"(a), "v"(b));
  return d;
}

// ---- clock probe: 16384 dependent FMAs. f_GHz ~= 16384*4 / (dur_ns) ----
// dur ~27us -> 2.4 GHz ; ~55us -> 1.2 GHz.
__global__ __launch_bounds__(64) void clock_probe(float* buf) {
  float x = (float)threadIdx.x * 1e-8f + 1.0f;
  float a = 1.0000001f, b = 1e-9f;
#pragma unroll 1
  for (int i = 0; i < 2048; ++i) {
#pragma unroll
    for (int j = 0; j < 8; ++j)
      asm volatile("v_fma_f32 %0, %0, %1, %2" : "+v"(x) : "v"(a), "v"(b));
  }
  if (x == 12345.678f) buf[0] = x;  // unreachable; keeps chain live
}

// ---- GEMM tile body: writes xproj rows [bt0, bt0+128) ----
__device__ __forceinline__ void gemm_tile(
    const float* __restrict__ A, const float* __restrict__ W,
    const float* __restrict__ b_ih, const float* __restrict__ b_hh,
    float* __restrict__ C, int bt0, float* sA, float* sB)
{
  const int tid = threadIdx.x;
  const int gt = tid & 15;
  const int btt = tid >> 4;
  float acc[8][8];
#pragma unroll
  for (int i = 0; i < 8; ++i)
#pragma unroll
    for (int j = 0; j < 8; ++j) acc[i][j] = 0.f;

  for (int kc = 0; kc < 8; ++kc) {
    const int k0 = kc * 32;
    __syncthreads();
#pragma unroll
    for (int i = 0; i < 16; ++i) {
      int s = i * 256 + tid;
      int r = s >> 5, cc = s & 31;
      sA[r * PAD + cc] = A[(size_t)(bt0 + r) * NIN + k0 + cc];
      sB[r * PAD + cc] = W[(size_t)r * NIN + k0 + cc];
    }
    __syncthreads();
#pragma unroll
    for (int k2 = 0; k2 < 16; ++k2) {
      float2 a2[8], b2[8];
#pragma unroll
      for (int i = 0; i < 8; ++i)
        a2[i] = *(const float2*)&sA[(btt + 16 * i) * PAD + 2 * k2];
#pragma unroll
      for (int j = 0; j < 8; ++j)
        b2[j] = *(const float2*)&sB[(gt + 16 * j) * PAD + 2 * k2];
#pragma unroll
      for (int i = 0; i < 8; ++i)
#pragma unroll
        for (int j = 0; j < 8; ++j) {
          acc[i][j] = fmaf(a2[i].x, b2[j].x, acc[i][j]);
          acc[i][j] = fmaf(a2[i].y, b2[j].y, acc[i][j]);
        }
    }
  }
  { // k = 256 tail
    float a[8], bb[8];
#pragma unroll
    for (int i = 0; i < 8; ++i) a[i] = A[(size_t)(bt0 + btt + 16 * i) * NIN + 256];
#pragma unroll
    for (int j = 0; j < 8; ++j) bb[j] = W[(size_t)(gt + 16 * j) * NIN + 256];
#pragma unroll
    for (int i = 0; i < 8; ++i)
#pragma unroll
      for (int j = 0; j < 8; ++j) acc[i][j] += a[i] * bb[j];
  }
  float bias[8];
#pragma unroll
  for (int j = 0; j < 8; ++j) bias[j] = b_ih[gt + 16 * j] + b_hh[gt + 16 * j];
#pragma unroll
  for (int i = 0; i < 8; ++i) {
    size_t row = (size_t)(bt0 + btt + 16 * i) * G4;
#pragma unroll
    for (int j = 0; j < 8; ++j) C[row + gt + 16 * j] = acc[i][j] + bias[j];
  }
}

__global__ __launch_bounds__(256) void xproj_gemm(
    const float* __restrict__ A, const float* __restrict__ W,
    const float* __restrict__ b_ih, const float* __restrict__ b_hh,
    float* __restrict__ C)
{
  __shared__ float sA[TBT * PAD];
  __shared__ float sB[G4 * PAD];
  const int idx = blockIdx.x;
  const int ti = idx >> 6, bb = idx & 63;
  gemm_tile(A, W, b_ih, b_hh, C, bb * T_LEN + ti * TBT, sA, sB);
}

// ---- scan2: 32 waves, each interleaves TWO independent batch chains ----
__global__ __launch_bounds__(64, 1) void scan2(
    const float* __restrict__ W_hh,
    const float* __restrict__ W_out,
    const float* __restrict__ b_out,
    float* __restrict__ out,
    const float* __restrict__ xproj)
{
  const int w = blockIdx.x;
  const int l = threadIdx.x;
  __builtin_amdgcn_s_setprio(3);

  // shared packed K-pair weights: wA rows l, wB rows l+64
  float2 wA[16], wB[16];
#pragma unroll
  for (int j = 0; j < 16; j += 2) {
    float4 v0 = *(const float4*)&W_hh[l * HID + 2 * j];
    wA[j]     = make_float2(v0.x, v0.y);
    wA[j + 1] = make_float2(v0.z, v0.w);
    float4 v1 = *(const float4*)&W_hh[(l + 64) * HID + 2 * j];
    wB[j]     = make_float2(v1.x, v1.y);
    wB[j + 1] = make_float2(v1.z, v1.w);
  }
  // lanes<32 compute tanh(g) via 2*sig(2g)-1: 2x folded into exp2 constant
  const float eB = (l < HID) ? -2.88539008f : -1.44269504f;

  float c0 = 0.f, h0 = 0.f, c1 = 0.f, h1 = 0.f;
  u64 hp0[16], hp1[16];
#pragma unroll
  for (int k = 0; k < 16; ++k) { hp0[k] = 0ull; hp1[k] = 0ull; }

  const float* xb0 = xproj + (size_t)(2 * w)     * T_LEN * G4;
  const float* xb1 = xproj + (size_t)(2 * w + 1) * T_LEN * G4;

  auto step = [&](float xa, float xg, float& c, float& h, u64* hp) {
    float2 aA[4], aB[4];
    aA[0] = make_float2(xa, 0.f);
    aB[0] = make_float2(xg, 0.f);
#pragma unroll
    for (int q = 1; q < 4; ++q) {
      aA[q] = make_float2(0.f, 0.f);
      aB[q] = make_float2(0.f, 0.f);
    }
#pragma unroll
    for (int j = 0; j < 16; j += 4) {
#pragma unroll
      for (int q = 0; q < 4; ++q) {
        pkfma2(aA[q], wA[j + q], hp[j + q]);
        pkfma2(aB[q], wB[j + q], hp[j + q]);
      }
    }
    float2 tA = pkadd(pkadd(aA[0], aA[1]), pkadd(aA[2], aA[3]));
    float2 tB = pkadd(pkadd(aB[0], aB[1]), pkadd(aB[2], aB[3]));
    float accA = tA.x + tA.y;                  // i (l<32) / f (l>=32)
    float accB = tB.x + tB.y;                  // g (l<32) / o (l>=32)
    float actA = __builtin_amdgcn_rcpf(1.f + __builtin_amdgcn_exp2f(-1.44269504f * accA));
    float sB2  = __builtin_amdgcn_rcpf(1.f + __builtin_amdgcn_exp2f(eB * accB));
    // lanes<32: prod = actA*(2*sB2-1) = i*tanh(g), one fused rounding
    float actA2 = actA + actA;                 // off critical path
    float prod  = fmaf(actA2, sB2, -actA);
    // measured semantics: swap(vdst=0, src=prod) -> dst_new[32+k] = prod[k]
    v2i sw = __builtin_amdgcn_permlane32_swap(0, __float_as_int(prod), false, false);
    float pr = __int_as_float(sw[0]);
    c = fmaf(actA, c, pr);                     // lanes>=32: c = f*c + i*g
    float t  = __builtin_amdgcn_rcpf(1.f + __builtin_amdgcn_exp2f(-2.88539008f * c));
    float s2 = sB2 + sB2;                      // off critical path (o = sB2 on l>=32)
    h = fmaf(s2, t, -sB2);                     // lanes>=32: h = o*tanh(c)
#pragma unroll
    for (int k = 0; k < 16; ++k) {
      unsigned lo = (unsigned)__builtin_amdgcn_readlane(__float_as_int(h), 32 + 2 * k);
      unsigned hi = (unsigned)__builtin_amdgcn_readlane(__float_as_int(h), 33 + 2 * k);
      hp[k] = (u64)lo | ((u64)hi << 32);
    }
  };

  float a0x[CH], a0g[CH], a1x[CH], a1g[CH];   // even chunk, batches 0/1
  float b0x[CH], b0g[CH], b1x[CH], b1g[CH];   // odd chunk

#define LOADC(px, pg, qx, qg, P0, P1, OFF) do { _Pragma("unroll") \
  for (int i = 0; i < CH; ++i) { \
    px[i] = (P0)[(size_t)((OFF) + i) * G4 + l]; \
    pg[i] = (P0)[(size_t)((OFF) + i) * G4 + 64 + l]; \
    qx[i] = (P1)[(size_t)((OFF) + i) * G4 + l]; \
    qg[i] = (P1)[(size_t)((OFF) + i) * G4 + 64 + l]; \
  } } while (0)

#define STEPS2(px, pg, qx, qg) do { _Pragma("unroll") \
  for (int i = 0; i < CH; ++i) { \
    step(px[i], pg[i], c0, h0, hp0); \
    step(qx[i], qg[i], c1, h1, hp1); \
  } } while (0)

#pragma unroll 1
  for (int ti = 0; ti < TPB; ++ti) {
    const float* p0 = xb0 + (size_t)ti * TBT * G4;
    const float* p1 = xb1 + (size_t)ti * TBT * G4;
    LOADC(a0x, a0g, a1x, a1g, p0, p1, 0);
#pragma unroll 1
    for (int ch = 0; ch < TBT / CH; ch += 2) {
      LOADC(b0x, b0g, b1x, b1g, p0, p1, (ch + 1) * CH);
      STEPS2(a0x, a0g, a1x, a1g);
      if (ch + 2 < TBT / CH)
        LOADC(a0x, a0g, a1x, a1g, p0, p1, (ch + 2) * CH);
      STEPS2(b0x, b0g, b1x, b1g);
    }
  }

  // head for both batches: logits = relu(h) @ W_out.T + b_out ; log_softmax
  float hf0[HID], hf1[HID];
#pragma unroll
  for (int k = 0; k < HID; ++k) {
    hf0[k] = __int_as_float(__builtin_amdgcn_readlane(__float_as_int(h0), 32 + k));
    hf1[k] = __int_as_float(__builtin_amdgcn_readlane(__float_as_int(h1), 32 + k));
  }
  float lg0 = 0.f, lg1 = 0.f;
  if (l < NOUT) {
    lg0 = b_out[l];
    lg1 = b_out[l];
#pragma unroll
    for (int j = 0; j < HID; ++j) {
      float wv = W_out[l * HID + j];
      lg0 += fmaxf(hf0[j], 0.f) * wv;
      lg1 += fmaxf(hf1[j], 0.f) * wv;
    }
  }
  float m0 = -1e30f, m1 = -1e30f;
#pragma unroll
  for (int n = 0; n < NOUT; ++n) {
    m0 = fmaxf(m0, __shfl(lg0, n));
    m1 = fmaxf(m1, __shfl(lg1, n));
  }
  float s0 = 0.f, s1 = 0.f;
#pragma unroll
  for (int n = 0; n < NOUT; ++n) {
    s0 += __builtin_amdgcn_exp2f(1.44269504089f * (__shfl(lg0, n) - m0));
    s1 += __builtin_amdgcn_exp2f(1.44269504089f * (__shfl(lg1, n) - m1));
  }
  if (l < NOUT) {
    out[(2 * w) * NOUT + l]     = lg0 - m0 - 0.69314718056f * __builtin_amdgcn_logf(s0);
    out[(2 * w + 1) * NOUT + l] = lg1 - m1 - 0.69314718056f * __builtin_amdgcn_logf(s1);
  }
}

extern "C" void kernel_launch(void* const* d_in, const int* in_sizes, int n_in,
                              void* d_out, int out_size, void* d_ws, size_t ws_size,
                              hipStream_t stream) {
  const float* specs = (const float*)d_in[0];
  const float* W_ih  = (const float*)d_in[1];
  const float* W_hh  = (const float*)d_in[2];
  const float* b_ih  = (const float*)d_in[3];
  const float* b_hh  = (const float*)d_in[4];
  const float* W_out = (const float*)d_in[5];
  const float* b_out = (const float*)d_in[6];
  float* outp  = (float*)d_out;
  float* xproj = (float*)d_ws;                       // 64 MB

  // Measurement round: clock probe (own dispatch -> dur reveals DVFS state),
  // then GEMM, then the 2-batch-per-wave ILP scan. Kernel boundaries provide
  // the release/acquire for xproj.
  clock_probe<<<1, 64, 0, stream>>>(xproj);
  xproj_gemm<<<NTILE, 256, 0, stream>>>(specs, W_ih, b_ih, b_hh, xproj);
  scan2<<<B_SZ / 2, 64, 0, stream>>>(W_hh, W_out, b_out, outp, xproj);
}

// Round 4
// 565.871 us; speedup vs baseline: 1.8746x; 1.8746x over previous
//
#include <hip/hip_runtime.h>

#define B_SZ 64
#define T_LEN 2048
#define NIN 257
#define HID 32
#define G4 128
#define NOUT 10

#define TBT 128         // rows per xproj tile
#define PAD 34
#define CH 8
#define NSCAN 64
#define NGEMMP 128      // 64 scan + 128 gemm = 192 blocks (<=1 per CU)
#define NTILE 1024      // 16 t-tiles * 64 batches
#define TPB 16          // t-tiles per batch

#define SC_SIG  -1.44269504f   // -log2(e): sigmoid via exp2
#define SC_TANH -2.88539008f   // -2*log2(e): tanh via 2*sig(2x)-1, fold into scale

typedef int v2i __attribute__((ext_vector_type(2)));
typedef unsigned long long u64;

// acc.x += w.x * h2.lo ; acc.y += w.y * h2.hi   (standard packed, no op_sel)
__device__ __forceinline__ void pkfma2(float2& acc, float2 w, u64 h2) {
  asm("v_pk_fma_f32 %0, %1, %2, %0" : "+v"(acc) : "v"(w), "s"(h2));
}

__device__ __forceinline__ float2 pkadd(float2 a, float2 b) {
  float2 d;
  asm("v_pk_add_f32 %0, %1, %2" : "=v"(d) : "v"(a), "v"(b));
  return d;
}

// ---- GEMM tile body: writes xproj rows [bt0, bt0+128) ----
// Output layout: per row t, 64 float2 pairs: pair[c] = (col c, col c+64),
// pre-scaled by the activation exp2 constant for that column group.
__device__ __forceinline__ void gemm_tile(
    const float* __restrict__ A, const float* __restrict__ W,
    const float* __restrict__ b_ih, const float* __restrict__ b_hh,
    float* __restrict__ C, int bt0, float* sA, float* sB)
{
  const int tid = threadIdx.x;
  const int gt = tid & 15;
  const int btt = tid >> 4;
  float acc[8][8];
#pragma unroll
  for (int i = 0; i < 8; ++i)
#pragma unroll
    for (int j = 0; j < 8; ++j) acc[i][j] = 0.f;

  for (int kc = 0; kc < 8; ++kc) {
    const int k0 = kc * 32;
    __syncthreads();
#pragma unroll
    for (int i = 0; i < 16; ++i) {
      int s = i * 256 + tid;
      int r = s >> 5, cc = s & 31;
      sA[r * PAD + cc] = A[(size_t)(bt0 + r) * NIN + k0 + cc];
      sB[r * PAD + cc] = W[(size_t)r * NIN + k0 + cc];
    }
    __syncthreads();
#pragma unroll
    for (int k2 = 0; k2 < 16; ++k2) {
      float2 a2[8], b2[8];
#pragma unroll
      for (int i = 0; i < 8; ++i)
        a2[i] = *(const float2*)&sA[(btt + 16 * i) * PAD + 2 * k2];
#pragma unroll
      for (int j = 0; j < 8; ++j)
        b2[j] = *(const float2*)&sB[(gt + 16 * j) * PAD + 2 * k2];
#pragma unroll
      for (int i = 0; i < 8; ++i)
#pragma unroll
        for (int j = 0; j < 8; ++j) {
          acc[i][j] = fmaf(a2[i].x, b2[j].x, acc[i][j]);
          acc[i][j] = fmaf(a2[i].y, b2[j].y, acc[i][j]);
        }
    }
  }
  { // k = 256 tail
    float a[8], bb[8];
#pragma unroll
    for (int i = 0; i < 8; ++i) a[i] = A[(size_t)(bt0 + btt + 16 * i) * NIN + 256];
#pragma unroll
    for (int j = 0; j < 8; ++j) bb[j] = W[(size_t)(gt + 16 * j) * NIN + 256];
#pragma unroll
    for (int i = 0; i < 8; ++i)
#pragma unroll
      for (int j = 0; j < 8; ++j) acc[i][j] += a[i] * bb[j];
  }
  float bias[8], sc[8];
  int off[8];
#pragma unroll
  for (int j = 0; j < 8; ++j) {
    const int col = gt + 16 * j;
    bias[j] = b_ih[col] + b_hh[col];
    sc[j] = ((col >> 5) == 2) ? SC_TANH : SC_SIG;   // g-columns get tanh fold
    off[j] = ((col & 63) << 1) + (col >> 6);        // paired layout
  }
#pragma unroll
  for (int i = 0; i < 8; ++i) {
    size_t row = (size_t)(bt0 + btt + 16 * i) * G4;
#pragma unroll
    for (int j = 0; j < 8; ++j) C[row + off[j]] = (acc[i][j] + bias[j]) * sc[j];
  }
}

// ---- Fused kernel: blocks [0,64) scan, [64,192) persistent GEMM ----
__global__ __launch_bounds__(256) void fused(
    const float* __restrict__ A,      // specs
    const float* __restrict__ W,      // W_ih
    const float* __restrict__ b_ih,
    const float* __restrict__ b_hh,
    const float* __restrict__ W_hh,
    const float* __restrict__ W_out,
    const float* __restrict__ b_out,
    float* __restrict__ out,
    float* __restrict__ xproj,
    int* __restrict__ flags,
    int nowait)
{
  __shared__ float sA[TBT * PAD];
  __shared__ float sB[G4 * PAD];
  const int bid = blockIdx.x;

  if (bid >= NSCAN) {
    // -------- producer: persistent GEMM, tile-major (ti*64 + b) --------
    const int p = bid - NSCAN;
    for (int idx = p; idx < NTILE; idx += NGEMMP) {
      const int ti = idx >> 6, bb = idx & 63;
      const int bt0 = bb * T_LEN + ti * TBT;
      gemm_tile(A, W, b_ih, b_hh, xproj, bt0, sA, sB);
      __threadfence();
      __syncthreads();
      if (threadIdx.x == 0)
        __hip_atomic_store(&flags[idx], 1, __ATOMIC_RELEASE, __HIP_MEMORY_SCOPE_AGENT);
    }
    return;
  }

  // -------- consumer: LSTM scan, one wave per batch element --------
  if (threadIdx.x >= 64) return;
  __builtin_amdgcn_s_setprio(3);
  const int b = bid;
  const int l = threadIdx.x;

  // packed K-pair weights, PRE-SCALED by the exp2 activation constant:
  // wA rows l (i/f): * SC_SIG ; wB rows l+64 (g/o): * SC_TANH / SC_SIG
  const float wsB = (l < HID) ? SC_TANH : SC_SIG;
  float2 wA[16], wB[16];
#pragma unroll
  for (int j = 0; j < 16; j += 2) {
    float4 v0 = *(const float4*)&W_hh[l * HID + 2 * j];
    wA[j]     = make_float2(v0.x * SC_SIG, v0.y * SC_SIG);
    wA[j + 1] = make_float2(v0.z * SC_SIG, v0.w * SC_SIG);
    float4 v1 = *(const float4*)&W_hh[(l + 64) * HID + 2 * j];
    wB[j]     = make_float2(v1.x * wsB, v1.y * wsB);
    wB[j + 1] = make_float2(v1.z * wsB, v1.w * wsB);
  }

  float c = 0.f, h = 0.f;
  u64 hp[16];
#pragma unroll
  for (int k = 0; k < 16; ++k) hp[k] = 0ull;

  const float2* xb2 = (const float2*)(xproj + (size_t)b * T_LEN * G4);

  auto step = [&](float xa, float xg) {
    // 4 independent chains of depth 4 per gate; accs arrive PRE-SCALED
    float2 aA[4], aB[4];
    aA[0] = make_float2(xa, 0.f);
    aB[0] = make_float2(xg, 0.f);
#pragma unroll
    for (int q = 1; q < 4; ++q) {
      aA[q] = make_float2(0.f, 0.f);
      aB[q] = make_float2(0.f, 0.f);
    }
#pragma unroll
    for (int j = 0; j < 16; j += 4) {
#pragma unroll
      for (int q = 0; q < 4; ++q) {
        pkfma2(aA[q], wA[j + q], hp[j + q]);
        pkfma2(aB[q], wB[j + q], hp[j + q]);
      }
    }
    float2 tA = pkadd(pkadd(aA[0], aA[1]), pkadd(aA[2], aA[3]));
    float2 tB = pkadd(pkadd(aB[0], aB[1]), pkadd(aB[2], aB[3]));
    float accA = tA.x + tA.y;                  // pre-scaled i (l<32) / f
    float accB = tB.x + tB.y;                  // pre-scaled 2g (l<32) / o
    float actA = __builtin_amdgcn_rcpf(1.f + __builtin_amdgcn_exp2f(accA));
    float sB2  = __builtin_amdgcn_rcpf(1.f + __builtin_amdgcn_exp2f(accB));
    // lanes<32: prod = actA*(2*sB2-1) = i*tanh(g)
    float actA2 = actA + actA;                 // off critical path
    float prod  = fmaf(actA2, sB2, -actA);
    // measured semantics: swap(vdst=0, src=prod) -> dst_new[32+k] = prod[k]
    v2i sw = __builtin_amdgcn_permlane32_swap(0, __float_as_int(prod), false, false);
    float pr = __int_as_float(sw[0]);
    c = fmaf(actA, c, pr);                     // lanes>=32: c = f*c + i*g
    float t  = __builtin_amdgcn_rcpf(1.f + __builtin_amdgcn_exp2f(SC_TANH * c));
    float s2 = sB2 + sB2;                      // off critical path (o = sB2 on l>=32)
    h = fmaf(s2, t, -sB2);                     // lanes>=32: h = o*tanh(c)
#pragma unroll
    for (int k = 0; k < 16; ++k) {
      unsigned lo = (unsigned)__builtin_amdgcn_readlane(__float_as_int(h), 32 + 2 * k);
      unsigned hi = (unsigned)__builtin_amdgcn_readlane(__float_as_int(h), 33 + 2 * k);
      hp[k] = (u64)lo | ((u64)hi << 32);
    }
  };

  float2 X0[CH], X1[CH];
#define LOADC2(X, P) do { _Pragma("unroll") \
  for (int i = 0; i < CH; ++i) X[i] = (P)[i * 64]; } while (0)
#define STEPS(X) do { _Pragma("unroll") \
  for (int i = 0; i < CH; ++i) step(X[i].x, X[i].y); } while (0)

  for (int ti = 0; ti < TPB; ++ti) {
    if (!nowait) {
      while (__hip_atomic_load(&flags[ti * 64 + b], __ATOMIC_ACQUIRE,
                               __HIP_MEMORY_SCOPE_AGENT) == 0)
        __builtin_amdgcn_s_sleep(2);
    }
    const float2* xt = xb2 + (size_t)ti * TBT * 64 + l;
    LOADC2(X0, xt);
#pragma unroll 1
    for (int ch = 0; ch < TBT / CH; ch += 2) {
      const float2* s1 = xt + (size_t)(ch + 1) * CH * 64;
      LOADC2(X1, s1);
      STEPS(X0);
      if (ch + 2 < TBT / CH) {
        const float2* s2 = xt + (size_t)(ch + 2) * CH * 64;
        LOADC2(X0, s2);
      }
      STEPS(X1);
    }
  }

  // head: logits = relu(h) @ W_out.T + b_out ; log_softmax  (shuffle-only)
  float hf[HID];
#pragma unroll
  for (int k = 0; k < HID; ++k)
    hf[k] = __int_as_float(__builtin_amdgcn_readlane(__float_as_int(h), 32 + k));
  float logit = 0.f;
  if (l < NOUT) {
    logit = b_out[l];
#pragma unroll
    for (int j = 0; j < HID; ++j) logit += fmaxf(hf[j], 0.f) * W_out[l * HID + j];
  }
  float m = -1e30f;
#pragma unroll
  for (int n = 0; n < NOUT; ++n) m = fmaxf(m, __shfl(logit, n));
  float s = 0.f;
#pragma unroll
  for (int n = 0; n < NOUT; ++n)
    s += __builtin_amdgcn_exp2f(1.44269504089f * (__shfl(logit, n) - m));
  if (l < NOUT)
    out[b * NOUT + l] = logit - m - 0.69314718056f * __builtin_amdgcn_logf(s);
}

// ---- fallback standalone GEMM (serial path if ws too small for flags) ----
__global__ __launch_bounds__(256) void xproj_gemm(
    const float* __restrict__ A, const float* __restrict__ W,
    const float* __restrict__ b_ih, const float* __restrict__ b_hh,
    float* __restrict__ C)
{
  __shared__ float sA[TBT * PAD];
  __shared__ float sB[G4 * PAD];
  const int idx = blockIdx.x;
  const int ti = idx >> 6, bb = idx & 63;
  gemm_tile(A, W, b_ih, b_hh, C, bb * T_LEN + ti * TBT, sA, sB);
}

extern "C" void kernel_launch(void* const* d_in, const int* in_sizes, int n_in,
                              void* d_out, int out_size, void* d_ws, size_t ws_size,
                              hipStream_t stream) {
  const float* specs = (const float*)d_in[0];
  const float* W_ih  = (const float*)d_in[1];
  const float* W_hh  = (const float*)d_in[2];
  const float* b_ih  = (const float*)d_in[3];
  const float* b_hh  = (const float*)d_in[4];
  const float* W_out = (const float*)d_in[5];
  const float* b_out = (const float*)d_in[6];
  float* outp  = (float*)d_out;
  float* xproj = (float*)d_ws;                       // 64 MB
  const size_t xbytes = (size_t)B_SZ * T_LEN * G4 * 4;

  if (ws_size >= xbytes + NTILE * sizeof(int)) {
    int* flags = (int*)((char*)d_ws + xbytes);
    (void)hipMemsetAsync(flags, 0, NTILE * sizeof(int), stream);
    fused<<<NSCAN + NGEMMP, 256, 0, stream>>>(specs, W_ih, b_ih, b_hh, W_hh,
                                              W_out, b_out, outp, xproj, flags, 0);
  } else {
    xproj_gemm<<<NTILE, 256, 0, stream>>>(specs, W_ih, b_ih, b_hh, xproj);
    fused<<<NSCAN, 256, 0, stream>>>(specs, W_ih, b_ih, b_hh, W_hh,
                                     W_out, b_out, outp, xproj, (int*)xproj /*unused*/, 1);
  }
}